// Round 2
// baseline (231.941 us; speedup 1.0000x reference)
//
#include <hip/hip_runtime.h>

#define NA 900
#define NP 13
#define NCAM 6
#define NL 4
#define NG 8
#define NC 256
#define TOTALHW 14960
#define NS (NP * NCAM * NL)  // 312 samples per anchor

__global__ __launch_bounds__(256) void daf_kernel(
    const float* __restrict__ feature,
    const int* __restrict__ spatial_shapes,
    const int* __restrict__ level_start,
    const float* __restrict__ points,
    const float* __restrict__ weights,
    float* __restrict__ out)
{
    const int a    = blockIdx.x;
    const int tid  = threadIdx.x;
    const int wv   = tid >> 6;   // wave 0..3
    const int lane = tid & 63;

    __shared__ int    s_idx[NS][4];
    __shared__ float  s_cw[NS][4];
    __shared__ float  s_wg[NS * NG];
    __shared__ float4 s_part[4][64];

    // ---- stage per-anchor group weights: [P][CAM][L][G] contiguous = 2496 floats
    const float* wsrc = weights + (size_t)a * NS * NG;
    for (int i = tid; i < NS * NG; i += 256) s_wg[i] = wsrc[i];

    // ---- build 312 sample descriptors (uniform over channels; do once per block)
    for (int s = tid; s < NS; s += 256) {
        const int l   = s & 3;       // level fastest (matches weights layout)
        const int pc  = s >> 2;
        const int cam = pc % NCAM;
        const int p   = pc / NCAM;

        const float2 pt = *(const float2*)(points + (((size_t)a * NP + p) * NCAM + cam) * 2);
        const int h  = spatial_shapes[l * 2 + 0];
        const int w  = spatial_shapes[l * 2 + 1];
        const int st = level_start[l];

        const float x   = pt.x * (float)w - 0.5f;
        const float y   = pt.y * (float)h - 0.5f;
        const float x0f = floorf(x);
        const float y0f = floorf(y);
        const int   x0  = (int)x0f;
        const int   y0  = (int)y0f;
        const float fx  = x - x0f;
        const float fy  = y - y0f;
        const float wx[2] = {1.0f - fx, fx};
        const float wy[2] = {1.0f - fy, fy};

        const int base = cam * TOTALHW + st;
        #pragma unroll
        for (int k = 0; k < 4; ++k) {
            const int dx = k & 1;
            const int dy = k >> 1;
            const int xi = x0 + dx;
            const int yi = y0 + dy;
            const bool valid = (xi >= 0) && (xi < w) && (yi >= 0) && (yi < h);
            const int xc = min(max(xi, 0), w - 1);
            const int yc = min(max(yi, 0), h - 1);
            s_idx[s][k] = base + yc * w + xc;
            s_cw[s][k]  = valid ? wx[dx] * wy[dy] : 0.0f;
        }
    }
    __syncthreads();

    // ---- gather + accumulate: lane owns channels [lane*4, lane*4+4); all 4 in one group
    const int g = lane >> 3;                       // (lane*4)/32
    const float4* __restrict__ f4 = (const float4*)feature;

    float4 acc = make_float4(0.f, 0.f, 0.f, 0.f);
    for (int s = wv; s < NS; s += 4) {
        const float wg = s_wg[s * NG + g];
        const int   i0 = s_idx[s][0], i1 = s_idx[s][1], i2 = s_idx[s][2], i3 = s_idx[s][3];
        const float c0 = s_cw[s][0],  c1 = s_cw[s][1],  c2 = s_cw[s][2],  c3 = s_cw[s][3];

        const float4 v0 = f4[(size_t)i0 * 64 + lane];
        const float4 v1 = f4[(size_t)i1 * 64 + lane];
        const float4 v2 = f4[(size_t)i2 * 64 + lane];
        const float4 v3 = f4[(size_t)i3 * 64 + lane];

        const float bx = v0.x * c0 + v1.x * c1 + v2.x * c2 + v3.x * c3;
        const float by = v0.y * c0 + v1.y * c1 + v2.y * c2 + v3.y * c3;
        const float bz = v0.z * c0 + v1.z * c1 + v2.z * c2 + v3.z * c3;
        const float bw = v0.w * c0 + v1.w * c1 + v2.w * c2 + v3.w * c3;

        acc.x += bx * wg;
        acc.y += by * wg;
        acc.z += bz * wg;
        acc.w += bw * wg;
    }

    s_part[wv][lane] = acc;
    __syncthreads();

    // ---- cross-wave reduction, float4 store
    if (tid < 64) {
        const float4 p0 = s_part[0][lane];
        const float4 p1 = s_part[1][lane];
        const float4 p2 = s_part[2][lane];
        const float4 p3 = s_part[3][lane];
        float4 r;
        r.x = (p0.x + p1.x) + (p2.x + p3.x);
        r.y = (p0.y + p1.y) + (p2.y + p3.y);
        r.z = (p0.z + p1.z) + (p2.z + p3.z);
        r.w = (p0.w + p1.w) + (p2.w + p3.w);
        ((float4*)out)[(size_t)a * 64 + lane] = r;
    }
}

extern "C" void kernel_launch(void* const* d_in, const int* in_sizes, int n_in,
                              void* d_out, int out_size, void* d_ws, size_t ws_size,
                              hipStream_t stream) {
    const float* feature        = (const float*)d_in[0];
    const int*   spatial_shapes = (const int*)d_in[1];
    const int*   level_start    = (const int*)d_in[2];
    const float* points         = (const float*)d_in[3];
    const float* weights        = (const float*)d_in[4];
    float*       out            = (float*)d_out;

    daf_kernel<<<NA, 256, 0, stream>>>(feature, spatial_shapes, level_start,
                                       points, weights, out);
}

// Round 3
// 230.243 us; speedup vs baseline: 1.0074x; 1.0074x over previous
//
#include <hip/hip_runtime.h>

#define NA 900
#define NP 13
#define NCAM 6
#define NL 4
#define NG 8
#define NC 256
#define TOTALHW 14960
#define NS (NP * NCAM * NL)  // 312 samples per anchor
#define NW 8                 // waves per block

__global__ __launch_bounds__(512) void daf_kernel(
    const float* __restrict__ feature,
    const int* __restrict__ spatial_shapes,
    const int* __restrict__ level_start,
    const float* __restrict__ points,
    const float* __restrict__ weights,
    float* __restrict__ out)
{
    const int a    = blockIdx.x;
    const int tid  = threadIdx.x;
    const int wv   = tid >> 6;   // wave 0..7
    const int lane = tid & 63;

    __shared__ int    s_idx[NS][4];
    __shared__ float  s_cw[NS][4];
    __shared__ float  s_wg[NS * NG];
    __shared__ float4 s_part[NW][64];

    // ---- stage per-anchor group weights: [P][CAM][L][G] contiguous = 2496 floats
    const float* wsrc = weights + (size_t)a * NS * NG;
    for (int i = tid; i < NS * NG; i += 512) s_wg[i] = wsrc[i];

    // ---- build 312 sample descriptors (uniform over channels; once per block)
    if (tid < NS) {
        const int s   = tid;
        const int l   = s & 3;       // level fastest (matches weights layout)
        const int pc  = s >> 2;
        const int cam = pc % NCAM;
        const int p   = pc / NCAM;

        const float2 pt = *(const float2*)(points + (((size_t)a * NP + p) * NCAM + cam) * 2);
        const int h  = spatial_shapes[l * 2 + 0];
        const int w  = spatial_shapes[l * 2 + 1];
        const int st = level_start[l];

        const float x   = pt.x * (float)w - 0.5f;
        const float y   = pt.y * (float)h - 0.5f;
        const float x0f = floorf(x);
        const float y0f = floorf(y);
        const int   x0  = (int)x0f;
        const int   y0  = (int)y0f;
        const float fx  = x - x0f;
        const float fy  = y - y0f;
        const float wx[2] = {1.0f - fx, fx};
        const float wy[2] = {1.0f - fy, fy};

        const int base = cam * TOTALHW + st;
        #pragma unroll
        for (int k = 0; k < 4; ++k) {
            const int dx = k & 1;
            const int dy = k >> 1;
            const int xi = x0 + dx;
            const int yi = y0 + dy;
            const bool valid = (xi >= 0) && (xi < w) && (yi >= 0) && (yi < h);
            const int xc = min(max(xi, 0), w - 1);
            const int yc = min(max(yi, 0), h - 1);
            s_idx[s][k] = base + yc * w + xc;
            s_cw[s][k]  = valid ? wx[dx] * wy[dy] : 0.0f;
        }
    }
    __syncthreads();

    // ---- gather + accumulate: lane owns channels [lane*4, lane*4+4); all in one group
    const int g = lane >> 3;                       // (lane*4)/32
    const float4* __restrict__ f4 = (const float4*)feature;

    float4 acc = make_float4(0.f, 0.f, 0.f, 0.f);
    for (int s = wv; s < NS; s += NW) {
        const float wg = s_wg[s * NG + g];
        const int   i0 = s_idx[s][0], i1 = s_idx[s][1], i2 = s_idx[s][2], i3 = s_idx[s][3];
        // fold group weight into the 4 corner weights: 4 mul + 16 fma per sample
        const float c0 = s_cw[s][0] * wg, c1 = s_cw[s][1] * wg;
        const float c2 = s_cw[s][2] * wg, c3 = s_cw[s][3] * wg;

        const float4 v0 = f4[(size_t)i0 * 64 + lane];
        const float4 v1 = f4[(size_t)i1 * 64 + lane];
        const float4 v2 = f4[(size_t)i2 * 64 + lane];
        const float4 v3 = f4[(size_t)i3 * 64 + lane];

        acc.x += v0.x * c0 + v1.x * c1 + v2.x * c2 + v3.x * c3;
        acc.y += v0.y * c0 + v1.y * c1 + v2.y * c2 + v3.y * c3;
        acc.z += v0.z * c0 + v1.z * c1 + v2.z * c2 + v3.z * c3;
        acc.w += v0.w * c0 + v1.w * c1 + v2.w * c2 + v3.w * c3;
    }

    s_part[wv][lane] = acc;
    __syncthreads();

    // ---- cross-wave reduction, float4 store
    if (tid < 64) {
        float4 r = s_part[0][lane];
        #pragma unroll
        for (int k = 1; k < NW; ++k) {
            const float4 p = s_part[k][lane];
            r.x += p.x; r.y += p.y; r.z += p.z; r.w += p.w;
        }
        ((float4*)out)[(size_t)a * 64 + lane] = r;
    }
}

extern "C" void kernel_launch(void* const* d_in, const int* in_sizes, int n_in,
                              void* d_out, int out_size, void* d_ws, size_t ws_size,
                              hipStream_t stream) {
    const float* feature        = (const float*)d_in[0];
    const int*   spatial_shapes = (const int*)d_in[1];
    const int*   level_start    = (const int*)d_in[2];
    const float* points         = (const float*)d_in[3];
    const float* weights        = (const float*)d_in[4];
    float*       out            = (float*)d_out;

    daf_kernel<<<NA, 512, 0, stream>>>(feature, spatial_shapes, level_start,
                                       points, weights, out);
}

// Round 4
// 214.531 us; speedup vs baseline: 1.0812x; 1.0732x over previous
//
#include <hip/hip_runtime.h>

#define NA 900
#define NP 13
#define NCAM 6
#define NL 4
#define NG 8
#define NC 256
#define TOTALHW 14960
#define NPC (NP * NCAM)      // 78 point-cam pairs
#define NS (NPC * NL)        // 312 samples per anchor
#define NW 8                 // waves per block

// static level metadata (LEVEL_SHAPES is compile-time constant in the reference)
__device__ __constant__ int c_h[NL]  = {64, 32, 16, 8};
__device__ __constant__ int c_w[NL]  = {176, 88, 44, 22};
__device__ __constant__ int c_st[NL] = {0, 11264, 14080, 14784};

__global__ __launch_bounds__(512) void daf_kernel(
    const float* __restrict__ feature,
    const int* __restrict__ spatial_shapes,
    const int* __restrict__ level_start,
    const float* __restrict__ points,
    const float* __restrict__ weights,
    float* __restrict__ out)
{
    const int a    = blockIdx.x;
    const int tid  = threadIdx.x;
    const int wv   = tid >> 6;   // wave 0..7
    const int lane = tid & 63;

    // descriptors stored LEVEL-MAJOR: s = l * NPC + pc
    __shared__ int    s_idx[NS][4];
    __shared__ float  s_cw[NS][4];
    __shared__ float  s_wg[NS * NG];
    __shared__ float4 s_part[NW][64];

    // ---- stage per-anchor group weights, remapped to level-major order
    // weights layout: [P][CAM][L][G]; target s_wg[(l*NPC+pc)*NG + g]
    const float* wsrc = weights + (size_t)a * NS * NG;
    for (int i = tid; i < NS * NG; i += 512) {
        const int g  = i & (NG - 1);
        const int s  = i >> 3;          // level-major sample id
        const int l  = s / NPC;
        const int pc = s - l * NPC;
        s_wg[i] = wsrc[(pc * NL + l) * NG + g];
    }

    // ---- build 312 sample descriptors (level-major; once per block)
    if (tid < NS) {
        const int s   = tid;
        const int l   = s / NPC;
        const int pc  = s - l * NPC;
        const int cam = pc % NCAM;
        const int p   = pc / NCAM;

        const float2 pt = *(const float2*)(points + (((size_t)a * NP + p) * NCAM + cam) * 2);
        const int h  = c_h[l];
        const int w  = c_w[l];
        const int st = c_st[l];

        const float x   = pt.x * (float)w - 0.5f;
        const float y   = pt.y * (float)h - 0.5f;
        const float x0f = floorf(x);
        const float y0f = floorf(y);
        const int   x0  = (int)x0f;
        const int   y0  = (int)y0f;
        const float fx  = x - x0f;
        const float fy  = y - y0f;
        const float wx[2] = {1.0f - fx, fx};
        const float wy[2] = {1.0f - fy, fy};

        const int base = cam * TOTALHW + st;
        #pragma unroll
        for (int k = 0; k < 4; ++k) {
            const int dx = k & 1;
            const int dy = k >> 1;
            const int xi = x0 + dx;
            const int yi = y0 + dy;
            const bool valid = (xi >= 0) && (xi < w) && (yi >= 0) && (yi < h);
            const int xc = min(max(xi, 0), w - 1);
            const int yc = min(max(yi, 0), h - 1);
            s_idx[s][k] = base + yc * w + xc;
            s_cw[s][k]  = valid ? wx[dx] * wy[dy] : 0.0f;
        }
    }
    __syncthreads();

    // ---- gather + accumulate, LEVEL-MAJOR so co-resident blocks share a
    // per-level working set (levels 3,2: ~5MB -> per-XCD L2 resident)
    const int g = lane >> 3;                       // (lane*4)/32
    const float4* __restrict__ f4 = (const float4*)feature;

    float4 acc = make_float4(0.f, 0.f, 0.f, 0.f);
    for (int s = wv; s < NS; s += NW) {
        const float wg = s_wg[s * NG + g];
        const int   i0 = s_idx[s][0], i1 = s_idx[s][1], i2 = s_idx[s][2], i3 = s_idx[s][3];
        const float c0 = s_cw[s][0] * wg, c1 = s_cw[s][1] * wg;
        const float c2 = s_cw[s][2] * wg, c3 = s_cw[s][3] * wg;

        const float4 v0 = f4[(size_t)i0 * 64 + lane];
        const float4 v1 = f4[(size_t)i1 * 64 + lane];
        const float4 v2 = f4[(size_t)i2 * 64 + lane];
        const float4 v3 = f4[(size_t)i3 * 64 + lane];

        acc.x += v0.x * c0 + v1.x * c1 + v2.x * c2 + v3.x * c3;
        acc.y += v0.y * c0 + v1.y * c1 + v2.y * c2 + v3.y * c3;
        acc.z += v0.z * c0 + v1.z * c1 + v2.z * c2 + v3.z * c3;
        acc.w += v0.w * c0 + v1.w * c1 + v2.w * c2 + v3.w * c3;
    }

    s_part[wv][lane] = acc;
    __syncthreads();

    // ---- cross-wave reduction, float4 store
    if (tid < 64) {
        float4 r = s_part[0][lane];
        #pragma unroll
        for (int k = 1; k < NW; ++k) {
            const float4 p = s_part[k][lane];
            r.x += p.x; r.y += p.y; r.z += p.z; r.w += p.w;
        }
        ((float4*)out)[(size_t)a * 64 + lane] = r;
    }
}

extern "C" void kernel_launch(void* const* d_in, const int* in_sizes, int n_in,
                              void* d_out, int out_size, void* d_ws, size_t ws_size,
                              hipStream_t stream) {
    const float* feature        = (const float*)d_in[0];
    const int*   spatial_shapes = (const int*)d_in[1];
    const int*   level_start    = (const int*)d_in[2];
    const float* points         = (const float*)d_in[3];
    const float* weights        = (const float*)d_in[4];
    float*       out            = (float*)d_out;

    daf_kernel<<<NA, 512, 0, stream>>>(feature, spatial_shapes, level_start,
                                       points, weights, out);
}

// Round 6
// 204.211 us; speedup vs baseline: 1.1358x; 1.0505x over previous
//
#include <hip/hip_runtime.h>

#define NA 900
#define NP 13
#define NCAM 6
#define NL 4
#define NG 8
#define NC 256
#define TOTALHW 14960
#define NPC (NP * NCAM)      // 78 point-cam pairs
#define NS (NPC * NL)        // 312 samples per anchor
#define NW 8                 // waves per block
#define FEAT_ELEMS (NCAM * TOTALHW * NC)   // 22,978,560 elements

// static level metadata (LEVEL_SHAPES is compile-time constant in the reference)
__device__ __constant__ int c_h[NL]  = {64, 32, 16, 8};
__device__ __constant__ int c_w[NL]  = {176, 88, 44, 22};
__device__ __constant__ int c_st[NL] = {0, 11264, 14080, 14784};

__device__ __forceinline__ float bfu(unsigned short u) {
    union { unsigned int i; float f; } x;
    x.i = ((unsigned int)u) << 16;
    return x.f;
}

// ---- prologue: f32 -> bf16 (round-to-nearest-even) streaming conversion
__global__ __launch_bounds__(256) void cvt_kernel(
    const float* __restrict__ src, unsigned short* __restrict__ dst)
{
    const int n4 = FEAT_ELEMS / 4;
    for (int i = blockIdx.x * 256 + threadIdx.x; i < n4; i += gridDim.x * 256) {
        const float4 v = ((const float4*)src)[i];
        ushort4 o;
        const float* pv = (const float*)&v;
        unsigned short* po = (unsigned short*)&o;
        #pragma unroll
        for (int k = 0; k < 4; ++k) {
            union { float f; unsigned int u; } x;
            x.f = pv[k];
            // RNE bf16 rounding
            unsigned int r = x.u + 0x7FFFu + ((x.u >> 16) & 1u);
            po[k] = (unsigned short)(r >> 16);
        }
        ((ushort4*)dst)[i] = o;
    }
}

// ---- main gather kernel over bf16 feature copy
__global__ __launch_bounds__(512) void daf_bf16_kernel(
    const unsigned short* __restrict__ featb,
    const float* __restrict__ points,
    const float* __restrict__ weights,
    float* __restrict__ out)
{
    const int a    = blockIdx.x;
    const int tid  = threadIdx.x;
    const int wv   = tid >> 6;   // wave 0..7
    const int lane = tid & 63;

    // descriptors stored LEVEL-MAJOR: s = l * NPC + pc
    __shared__ int    s_idx[NS][4];
    __shared__ float  s_cw[NS][4];
    __shared__ float  s_wg[NS * NG];
    __shared__ float4 s_part[NW][64];

    // stage per-anchor group weights, remapped to level-major order
    const float* wsrc = weights + (size_t)a * NS * NG;
    for (int i = tid; i < NS * NG; i += 512) {
        const int g  = i & (NG - 1);
        const int s  = i >> 3;          // level-major sample id
        const int l  = s / NPC;
        const int pc = s - l * NPC;
        s_wg[i] = wsrc[(pc * NL + l) * NG + g];
    }

    // build 312 sample descriptors (level-major; once per block)
    if (tid < NS) {
        const int s   = tid;
        const int l   = s / NPC;
        const int pc  = s - l * NPC;
        const int cam = pc % NCAM;
        const int p   = pc / NCAM;

        const float2 pt = *(const float2*)(points + (((size_t)a * NP + p) * NCAM + cam) * 2);
        const int h  = c_h[l];
        const int w  = c_w[l];
        const int st = c_st[l];

        const float x   = pt.x * (float)w - 0.5f;
        const float y   = pt.y * (float)h - 0.5f;
        const float x0f = floorf(x);
        const float y0f = floorf(y);
        const int   x0  = (int)x0f;
        const int   y0  = (int)y0f;
        const float fx  = x - x0f;
        const float fy  = y - y0f;
        const float wx[2] = {1.0f - fx, fx};
        const float wy[2] = {1.0f - fy, fy};

        const int base = cam * TOTALHW + st;
        #pragma unroll
        for (int k = 0; k < 4; ++k) {
            const int dx = k & 1;
            const int dy = k >> 1;
            const int xi = x0 + dx;
            const int yi = y0 + dy;
            const bool valid = (xi >= 0) && (xi < w) && (yi >= 0) && (yi < h);
            const int xc = min(max(xi, 0), w - 1);
            const int yc = min(max(yi, 0), h - 1);
            s_idx[s][k] = base + yc * w + xc;
            s_cw[s][k]  = valid ? wx[dx] * wy[dy] : 0.0f;
        }
    }
    __syncthreads();

    // gather + accumulate, level-major. Each lane owns channels [lane*4, lane*4+4)
    // as one ushort4 (8B) load per corner row: 512B/wave/instruction.
    const int g = lane >> 3;                       // (lane*4)/32
    const ushort4* __restrict__ fb = (const ushort4*)featb;

    float4 acc = make_float4(0.f, 0.f, 0.f, 0.f);
    #pragma unroll 2
    for (int s = wv; s < NS; s += NW) {
        const float wg = s_wg[s * NG + g];
        const int   i0 = s_idx[s][0], i1 = s_idx[s][1], i2 = s_idx[s][2], i3 = s_idx[s][3];
        const float c0 = s_cw[s][0] * wg, c1 = s_cw[s][1] * wg;
        const float c2 = s_cw[s][2] * wg, c3 = s_cw[s][3] * wg;

        const ushort4 r0 = fb[(size_t)i0 * 64 + lane];
        const ushort4 r1 = fb[(size_t)i1 * 64 + lane];
        const ushort4 r2 = fb[(size_t)i2 * 64 + lane];
        const ushort4 r3 = fb[(size_t)i3 * 64 + lane];

        acc.x += bfu(r0.x) * c0 + bfu(r1.x) * c1 + bfu(r2.x) * c2 + bfu(r3.x) * c3;
        acc.y += bfu(r0.y) * c0 + bfu(r1.y) * c1 + bfu(r2.y) * c2 + bfu(r3.y) * c3;
        acc.z += bfu(r0.z) * c0 + bfu(r1.z) * c1 + bfu(r2.z) * c2 + bfu(r3.z) * c3;
        acc.w += bfu(r0.w) * c0 + bfu(r1.w) * c1 + bfu(r2.w) * c2 + bfu(r3.w) * c3;
    }

    s_part[wv][lane] = acc;
    __syncthreads();

    if (tid < 64) {
        float4 r = s_part[0][lane];
        #pragma unroll
        for (int k = 1; k < NW; ++k) {
            const float4 p = s_part[k][lane];
            r.x += p.x; r.y += p.y; r.z += p.z; r.w += p.w;
        }
        ((float4*)out)[(size_t)a * 64 + lane] = r;
    }
}

// ---- fallback: proven f32 kernel (used only if ws_size < bf16 copy size)
__global__ __launch_bounds__(512) void daf_f32_kernel(
    const float* __restrict__ feature,
    const float* __restrict__ points,
    const float* __restrict__ weights,
    float* __restrict__ out)
{
    const int a    = blockIdx.x;
    const int tid  = threadIdx.x;
    const int wv   = tid >> 6;
    const int lane = tid & 63;

    __shared__ int    s_idx[NS][4];
    __shared__ float  s_cw[NS][4];
    __shared__ float  s_wg[NS * NG];
    __shared__ float4 s_part[NW][64];

    const float* wsrc = weights + (size_t)a * NS * NG;
    for (int i = tid; i < NS * NG; i += 512) {
        const int g  = i & (NG - 1);
        const int s  = i >> 3;
        const int l  = s / NPC;
        const int pc = s - l * NPC;
        s_wg[i] = wsrc[(pc * NL + l) * NG + g];
    }

    if (tid < NS) {
        const int s   = tid;
        const int l   = s / NPC;
        const int pc  = s - l * NPC;
        const int cam = pc % NCAM;
        const int p   = pc / NCAM;

        const float2 pt = *(const float2*)(points + (((size_t)a * NP + p) * NCAM + cam) * 2);
        const int h  = c_h[l];
        const int w  = c_w[l];
        const int st = c_st[l];

        const float x   = pt.x * (float)w - 0.5f;
        const float y   = pt.y * (float)h - 0.5f;
        const float x0f = floorf(x);
        const float y0f = floorf(y);
        const int   x0  = (int)x0f;
        const int   y0  = (int)y0f;
        const float fx  = x - x0f;
        const float fy  = y - y0f;
        const float wx[2] = {1.0f - fx, fx};
        const float wy[2] = {1.0f - fy, fy};

        const int base = cam * TOTALHW + st;
        #pragma unroll
        for (int k = 0; k < 4; ++k) {
            const int dx = k & 1;
            const int dy = k >> 1;
            const int xi = x0 + dx;
            const int yi = y0 + dy;
            const bool valid = (xi >= 0) && (xi < w) && (yi >= 0) && (yi < h);
            const int xc = min(max(xi, 0), w - 1);
            const int yc = min(max(yi, 0), h - 1);
            s_idx[s][k] = base + yc * w + xc;
            s_cw[s][k]  = valid ? wx[dx] * wy[dy] : 0.0f;
        }
    }
    __syncthreads();

    const int g = lane >> 3;
    const float4* __restrict__ f4 = (const float4*)feature;

    float4 acc = make_float4(0.f, 0.f, 0.f, 0.f);
    for (int s = wv; s < NS; s += NW) {
        const float wg = s_wg[s * NG + g];
        const int   i0 = s_idx[s][0], i1 = s_idx[s][1], i2 = s_idx[s][2], i3 = s_idx[s][3];
        const float c0 = s_cw[s][0] * wg, c1 = s_cw[s][1] * wg;
        const float c2 = s_cw[s][2] * wg, c3 = s_cw[s][3] * wg;

        const float4 v0 = f4[(size_t)i0 * 64 + lane];
        const float4 v1 = f4[(size_t)i1 * 64 + lane];
        const float4 v2 = f4[(size_t)i2 * 64 + lane];
        const float4 v3 = f4[(size_t)i3 * 64 + lane];

        acc.x += v0.x * c0 + v1.x * c1 + v2.x * c2 + v3.x * c3;
        acc.y += v0.y * c0 + v1.y * c1 + v2.y * c2 + v3.y * c3;
        acc.z += v0.z * c0 + v1.z * c1 + v2.z * c2 + v3.z * c3;
        acc.w += v0.w * c0 + v1.w * c1 + v2.w * c2 + v3.w * c3;
    }

    s_part[wv][lane] = acc;
    __syncthreads();

    if (tid < 64) {
        float4 r = s_part[0][lane];
        #pragma unroll
        for (int k = 1; k < NW; ++k) {
            const float4 p = s_part[k][lane];
            r.x += p.x; r.y += p.y; r.z += p.z; r.w += p.w;
        }
        ((float4*)out)[(size_t)a * 64 + lane] = r;
    }
}

extern "C" void kernel_launch(void* const* d_in, const int* in_sizes, int n_in,
                              void* d_out, int out_size, void* d_ws, size_t ws_size,
                              hipStream_t stream) {
    const float* feature        = (const float*)d_in[0];
    const float* points         = (const float*)d_in[3];
    const float* weights        = (const float*)d_in[4];
    float*       out            = (float*)d_out;

    const size_t need = (size_t)FEAT_ELEMS * sizeof(unsigned short);  // ~46 MB
    if (ws_size >= need && d_ws != nullptr) {
        unsigned short* featb = (unsigned short*)d_ws;
        cvt_kernel<<<2048, 256, 0, stream>>>(feature, featb);
        daf_bf16_kernel<<<NA, 512, 0, stream>>>(featb, points, weights, out);
    } else {
        daf_f32_kernel<<<NA, 512, 0, stream>>>(feature, points, weights, out);
    }
}